// Round 1
// 539.005 us; speedup vs baseline: 1.0112x; 1.0112x over previous
//
#include <hip/hip_runtime.h>
#include <math.h>

#define B_  8
#define N_  128
#define T_  64
#define D_  512
#define H_  8
#define HD_ 64

typedef __attribute__((ext_vector_type(4))) float  f32x4;
typedef __attribute__((ext_vector_type(8))) __bf16 bf16x8;

__device__ __forceinline__ void async_copy16(const void* g, void* l) {
  __builtin_amdgcn_global_load_lds(
      (const __attribute__((address_space(1))) unsigned int*)g,
      (__attribute__((address_space(3))) unsigned int*)l, 16, 0, 0);
}

// ---------------------------------------------------------------------------
// K1: z_map = mean over T of h_map  [B*N, D]  (f32x4 vectorized, 2 t-halves)
// ---------------------------------------------------------------------------
__global__ __launch_bounds__(256) void zmap_kernel(const float* __restrict__ hmap,
                                                   float* __restrict__ z) {
  __shared__ f32x4 red[128];
  const int bn = blockIdx.x;
  const int c4 = threadIdx.x & 127;   // f32x4 chunk of D (512/4 = 128)
  const int th = threadIdx.x >> 7;    // t-half
  const float* src = hmap + (size_t)bn * (T_ * D_) + (size_t)th * 32 * D_ + c4 * 4;
  f32x4 s = {0.f, 0.f, 0.f, 0.f};
#pragma unroll 8
  for (int t = 0; t < 32; t++) {
    f32x4 v = *(const f32x4*)&src[(size_t)t * D_];
    s = s + v;
  }
  if (th) red[c4] = s;
  __syncthreads();
  if (!th) {
    f32x4 r = red[c4];
    f32x4 o = (s + r) * (1.f / 64.f);
    *(f32x4*)&z[(size_t)bn * D_ + c4 * 4] = o;
  }
}

// ---------------------------------------------------------------------------
// fp32 -> bf16 pre-convert (n multiple of 2048; grid = n/2048)  [weights only]
// ---------------------------------------------------------------------------
__global__ __launch_bounds__(256) void cvt_kernel(const float* __restrict__ s,
                                                  __bf16* __restrict__ d) {
  size_t i = ((size_t)blockIdx.x * 256 + threadIdx.x) << 3;
  f32x4 a = *(const f32x4*)&s[i];
  f32x4 b = *(const f32x4*)&s[i + 4];
  bf16x8 o;
  o[0] = (__bf16)a[0]; o[1] = (__bf16)a[1]; o[2] = (__bf16)a[2]; o[3] = (__bf16)a[3];
  o[4] = (__bf16)b[0]; o[5] = (__bf16)b[1]; o[6] = (__bf16)b[2]; o[7] = (__bf16)b[3];
  *(bf16x8*)&d[i] = o;
}

// ---------------------------------------------------------------------------
// K2: small q/k projection GEMM (M=1024), fp32 A/W, 64x64 tile
// ---------------------------------------------------------------------------
__global__ __launch_bounds__(256) void qk_gemm(const float* __restrict__ A,
    const float* __restrict__ W, float* __restrict__ Out) {
  __shared__ __bf16 As[64][72];
  __shared__ __bf16 Bs[64][72];
  const int tid  = threadIdx.x;
  const int n0   = blockIdx.x * 64;
  const int m0   = blockIdx.y * 64;
  const int lane = tid & 63, wv = tid >> 6;
  const int quad = lane >> 4, l15 = lane & 15;
  const int sr   = tid >> 2;
  f32x4 acc[4] = {};
  for (int kc = 0; kc < 512; kc += 64) {
#pragma unroll
    for (int i = 0; i < 4; i++) {
      int c = ((tid & 3) << 2) + (i << 4);
      f32x4 v = *(const f32x4*)&A[(size_t)(m0 + sr) * 512 + kc + c];
      As[sr][c + 0] = (__bf16)v[0]; As[sr][c + 1] = (__bf16)v[1];
      As[sr][c + 2] = (__bf16)v[2]; As[sr][c + 3] = (__bf16)v[3];
      f32x4 w = *(const f32x4*)&W[(size_t)(n0 + sr) * 512 + kc + c];
      Bs[sr][c + 0] = (__bf16)w[0]; Bs[sr][c + 1] = (__bf16)w[1];
      Bs[sr][c + 2] = (__bf16)w[2]; Bs[sr][c + 3] = (__bf16)w[3];
    }
    __syncthreads();
#pragma unroll
    for (int ks = 0; ks < 64; ks += 32) {
      bf16x8 a = *(const bf16x8*)&As[(wv << 4) + l15][ks + (quad << 3)];
#pragma unroll
      for (int ct = 0; ct < 4; ct++) {
        bf16x8 b = *(const bf16x8*)&Bs[(ct << 4) + l15][ks + (quad << 3)];
        acc[ct] = __builtin_amdgcn_mfma_f32_16x16x32_bf16(a, b, acc[ct], 0, 0, 0);
      }
    }
    __syncthreads();
  }
#pragma unroll
  for (int ct = 0; ct < 4; ct++)
#pragma unroll
    for (int r = 0; r < 4; r++) {
      const size_t m = (size_t)m0 + (wv << 4) + (quad << 2) + r;
      const size_t n = (size_t)n0 + (ct << 4) + l15;
      Out[m * 512 + n] = acc[ct][r];
    }
}

// ---------------------------------------------------------------------------
// Big GEMM: C = A @ W^T, 128x128 tile, BK=64, XOR-swizzled 16B granules.
//   MODE 1: A is fp32 h_val (converted to bf16 during reg-staging);
//           Out bf16 scattered to v[B,H,N,T,HD]
//   MODE 2: A bf16 (mixed); Out fp32 = h_val + acc*clamp(scale)
// grid: (4 n-tiles, 512 m-tiles), block 256 (4 waves, each 64x64 output)
// ---------------------------------------------------------------------------
template<int MODE>
__global__ __launch_bounds__(256) void gemm128(const __bf16* __restrict__ A,
    const float* __restrict__ Af, const __bf16* __restrict__ Wb,
    void* __restrict__ Out, const float* __restrict__ hval,
    const float* __restrict__ rscale) {
  __align__(16) __shared__ __bf16 As[128 * 64];
  __align__(16) __shared__ __bf16 Bs[128 * 64];
  const int tid = threadIdx.x;
  const int lane = tid & 63, wv = tid >> 6;
  const int n0 = blockIdx.x << 7;
  const int m0 = blockIdx.y << 7;
  const int quad = lane >> 4, l15 = lane & 15;
  const int mq = (wv >> 1) << 6, nq = (wv & 1) << 6;
  f32x4 acc[4][4] = {};

  // wave-uniform residual scale (MODE 2 only): all rows of this wave share
  // i = (m0+mq)>>6 since the wave's 64-row slab is 64-aligned.
  float sc = 0.f;
  if (MODE == 2) sc = fminf(fmaxf(rscale[((m0 + mq) >> 6) & 127], 0.f), 1.f);

  for (int kc = 0; kc < 512; kc += 64) {
    if (MODE == 1) {
      // B: async 16B granules (swizzled source chunk, linear LDS dest)
#pragma unroll
      for (int it = 0; it < 4; it++) {
        const int gb = (wv << 8) + (it << 6);
        const int s  = gb + lane;
        const int m  = s >> 3, c = (s & 7) ^ (m & 7);
        async_copy16(Wb + (size_t)(n0 + m) * 512 + kc + (c << 3), &Bs[gb << 3]);
      }
      // A: fp32 global -> bf16 cvt -> swizzled ds_write_b128 (fuses cvt pass)
#pragma unroll
      for (int it = 0; it < 4; it++) {
        const int s  = (wv << 8) + (it << 6) + lane;
        const int m  = s >> 3, cp = s & 7;
        const float* src = Af + (size_t)(m0 + m) * 512 + kc + (cp << 3);
        f32x4 u0 = *(const f32x4*)src;
        f32x4 u1 = *(const f32x4*)(src + 4);
        bf16x8 o;
        o[0] = (__bf16)u0[0]; o[1] = (__bf16)u0[1];
        o[2] = (__bf16)u0[2]; o[3] = (__bf16)u0[3];
        o[4] = (__bf16)u1[0]; o[5] = (__bf16)u1[1];
        o[6] = (__bf16)u1[2]; o[7] = (__bf16)u1[3];
        *(bf16x8*)&As[((m << 3) + (cp ^ (m & 7))) << 3] = o;
      }
    } else {
#pragma unroll
      for (int it = 0; it < 4; it++) {
        const int gb = (wv << 8) + (it << 6);
        const int s  = gb + lane;
        const int m  = s >> 3, c = (s & 7) ^ (m & 7);
        async_copy16(A  + (size_t)(m0 + m) * 512 + kc + (c << 3), &As[gb << 3]);
        async_copy16(Wb + (size_t)(n0 + m) * 512 + kc + (c << 3), &Bs[gb << 3]);
      }
    }
    __syncthreads();
#pragma unroll
    for (int k0 = 0; k0 < 64; k0 += 32) {
      const int cc = (k0 >> 3) + quad;           // chunk index 0..7
      bf16x8 af[4], bfr[4];
#pragma unroll
      for (int mt = 0; mt < 4; mt++) {
        int m = mq + (mt << 4) + l15;
        af[mt] = *(const bf16x8*)&As[((m << 3) + (cc ^ (m & 7))) << 3];
      }
#pragma unroll
      for (int nt = 0; nt < 4; nt++) {
        int n = nq + (nt << 4) + l15;
        bfr[nt] = *(const bf16x8*)&Bs[((n << 3) + (cc ^ (n & 7))) << 3];
      }
#pragma unroll
      for (int mt = 0; mt < 4; mt++)
#pragma unroll
        for (int nt = 0; nt < 4; nt++)
          acc[mt][nt] = __builtin_amdgcn_mfma_f32_16x16x32_bf16(af[mt], bfr[nt],
                                                                acc[mt][nt], 0, 0, 0);
    }
    __syncthreads();
  }

#pragma unroll
  for (int mt = 0; mt < 4; mt++)
#pragma unroll
    for (int nt = 0; nt < 4; nt++)
#pragma unroll
      for (int r = 0; r < 4; r++) {
        const size_t m = (size_t)m0 + mq + (mt << 4) + (quad << 2) + r;
        const size_t n = (size_t)n0 + nq + (nt << 4) + l15;
        float val = acc[mt][nt][r];
        if (MODE == 1) {
          size_t b = m >> 13, j = (m >> 6) & 127, tt = m & 63;
          size_t h = n >> 6, e = n & 63;
          ((__bf16*)Out)[(((b * 8 + h) * 128 + j) * 64 + tt) * 64 + e] = (__bf16)val;
        } else {
          ((float*)Out)[m * 512 + n] = hval[m * 512 + n] + val * sc;
        }
      }
}

// ---------------------------------------------------------------------------
// K3: scores + bias + raw softmax + top-16 softmax. One wave per row i.
// grid: (32 i-groups, 64 bh); block 256 (4 waves).
// ---------------------------------------------------------------------------
__global__ __launch_bounds__(256) void scores_kernel(
    const float* __restrict__ qb, const float* __restrict__ kb,
    const float* __restrict__ adj, __bf16* __restrict__ attnw,
    float* __restrict__ attn_mean, float* __restrict__ raw_mean) {
  __shared__ float  qs[4][64];
  __shared__ __bf16 ks_[128][66];
  const int ig = blockIdx.x, bh = blockIdx.y;
  const int b = bh >> 3, h = bh & 7;
  const int tid = threadIdx.x;
  {
    int r = tid >> 1, cb = (tid & 1) << 5;
    const float* ksrc = kb + ((size_t)(b * 128 + r)) * 512 + h * 64 + cb;
#pragma unroll
    for (int v = 0; v < 8; v++) {
      f32x4 kv = *(const f32x4*)&ksrc[v * 4];
      ks_[r][cb + v * 4 + 0] = (__bf16)kv[0];
      ks_[r][cb + v * 4 + 1] = (__bf16)kv[1];
      ks_[r][cb + v * 4 + 2] = (__bf16)kv[2];
      ks_[r][cb + v * 4 + 3] = (__bf16)kv[3];
    }
  }
  {
    int r = tid >> 6, ln = tid & 63;
    qs[r][ln] = qb[((size_t)(b * 128 + (ig << 2) + r)) * 512 + h * 64 + ln];
  }
  __syncthreads();
  const int wv = tid >> 6, lane = tid & 63;
  const int i = (ig << 2) + wv;
  const int j0 = lane, j1 = lane + 64;
  float s0 = 0.f, s1 = 0.f;
#pragma unroll 16
  for (int e = 0; e < 64; e++) {
    float qe = qs[wv][e];
    s0 += qe * (float)ks_[j0][e];
    s1 += qe * (float)ks_[j1][e];
  }
  const size_t arow = ((size_t)b * 128 + i) * 128;
  s0 = s0 * 0.125f + logf(fmaxf(adj[arow + j0], 1e-12f));
  s1 = s1 * 0.125f + logf(fmaxf(adj[arow + j1], 1e-12f));
  // raw softmax over 128
  float mx = fmaxf(s0, s1);
#pragma unroll
  for (int off = 32; off; off >>= 1) mx = fmaxf(mx, __shfl_xor(mx, off));
  float e0 = expf(s0 - mx), e1 = expf(s1 - mx);
  float sum = e0 + e1;
#pragma unroll
  for (int off = 32; off; off >>= 1) sum += __shfl_xor(sum, off);
  float inv = 0.125f / sum;
  atomicAdd(&raw_mean[arow + j0], e0 * inv);
  atomicAdd(&raw_mean[arow + j1], e1 * inv);
  // top-16 (ties -> lowest index, matching jax.lax.top_k)
  float w0 = s0, w1 = s1;
  bool sel0 = false, sel1 = false;
  float m16 = 0.f, denom = 0.f;
  for (int it = 0; it < 16; it++) {
    float v; int idx;
    if (w1 > w0) { v = w1; idx = j1; } else { v = w0; idx = j0; }
#pragma unroll
    for (int off = 32; off; off >>= 1) {
      float ov = __shfl_xor(v, off);
      int   oi = __shfl_xor(idx, off);
      if (ov > v || (ov == v && oi < idx)) { v = ov; idx = oi; }
    }
    if (it == 0) m16 = v;
    denom += expf(v - m16);
    if (idx == j0) { sel0 = true; w0 = -INFINITY; }
    if (idx == j1) { sel1 = true; w1 = -INFINITY; }
  }
  const float invd = 1.f / denom;
  const float p0 = sel0 ? expf(s0 - m16) * invd : 0.f;
  const float p1 = sel1 ? expf(s1 - m16) * invd : 0.f;
  const size_t ab = ((size_t)bh * 128 + i) * 128;
  attnw[ab + j0] = (__bf16)p0;
  attnw[ab + j1] = (__bf16)p1;
  if (sel0) atomicAdd(&attn_mean[arow + j0], p0 * 0.125f);
  if (sel1) atomicAdd(&attn_mean[arow + j1], p1 * 0.125f);
}

// ---------------------------------------------------------------------------
// K4: mixed = attn @ V dense MFMA per (b,h). grid (64 n-tiles, 64 bh).
// ---------------------------------------------------------------------------
__global__ __launch_bounds__(256) void mix_kernel(
    const __bf16* __restrict__ attnw, const __bf16* __restrict__ vbuf,
    __bf16* __restrict__ mixed) {
  __shared__ __bf16 As[128][136];
  __shared__ __bf16 Bt[64][136];
  const int nt = blockIdx.x;
  const int bh = blockIdx.y;
  const int b = bh >> 3, h = bh & 7;
  const int n0 = nt << 6;
  const int tid = threadIdx.x;
  {
    int i = tid >> 1, cb = (tid & 1) << 6;
    const __bf16* src = attnw + ((size_t)bh * 128 + i) * 128 + cb;
#pragma unroll
    for (int v = 0; v < 8; v++)
      *(bf16x8*)&As[i][cb + (v << 3)] = *(const bf16x8*)&src[v << 3];
  }
  {
    int j = tid >> 1, cb = (tid & 1) << 5;
    const __bf16* src = vbuf + ((size_t)bh * 128 + j) * 4096 + n0 + cb;
#pragma unroll
    for (int v = 0; v < 4; v++) {
      bf16x8 x = *(const bf16x8*)&src[v << 3];
#pragma unroll
      for (int u = 0; u < 8; u++) Bt[cb + (v << 3) + u][j] = x[u];
    }
  }
  __syncthreads();
  const int lane = tid & 63, wv = tid >> 6;
  const int quad = lane >> 4, l15 = lane & 15;
  f32x4 acc[2][4] = {};
#pragma unroll
  for (int kk = 0; kk < 128; kk += 32) {
    bf16x8 a0 = *(const bf16x8*)&As[(wv << 5) + l15][kk + (quad << 3)];
    bf16x8 a1 = *(const bf16x8*)&As[(wv << 5) + 16 + l15][kk + (quad << 3)];
#pragma unroll
    for (int ct = 0; ct < 4; ct++) {
      bf16x8 bb = *(const bf16x8*)&Bt[(ct << 4) + l15][kk + (quad << 3)];
      acc[0][ct] = __builtin_amdgcn_mfma_f32_16x16x32_bf16(a0, bb, acc[0][ct], 0, 0, 0);
      acc[1][ct] = __builtin_amdgcn_mfma_f32_16x16x32_bf16(a1, bb, acc[1][ct], 0, 0, 0);
    }
  }
  const int tt = nt;
#pragma unroll
  for (int rt = 0; rt < 2; rt++)
#pragma unroll
    for (int ct = 0; ct < 4; ct++)
#pragma unroll
      for (int r = 0; r < 4; r++) {
        int i = (wv << 5) + (rt << 4) + (quad << 2) + r;
        int e = (ct << 4) + l15;
        mixed[(((size_t)b * 128 + i) * 64 + tt) * 512 + h * 64 + e] =
            (__bf16)acc[rt][ct][r];
      }
}

// ---------------------------------------------------------------------------
extern "C" void kernel_launch(void* const* d_in, const int* in_sizes, int n_in,
                              void* d_out, int out_size, void* d_ws, size_t ws_size,
                              hipStream_t stream) {
  (void)in_sizes; (void)n_in; (void)out_size; (void)ws_size;
  const float* h_val = (const float*)d_in[0];
  const float* h_map = (const float*)d_in[1];
  const float* adj   = (const float*)d_in[2];
  const float* q_w   = (const float*)d_in[3];
  const float* k_w   = (const float*)d_in[4];
  const float* v_w   = (const float*)d_in[5];
  const float* o_w   = (const float*)d_in[6];
  const float* rsc   = (const float*)d_in[7];

  char* ws = (char*)d_ws;
  float*  zmap  = (float*)(ws);                         // 2 MiB (dead after qk gemms)
  __bf16* vwb   = (__bf16*)(ws);                        // 512 KiB (aliases zmap)
  __bf16* owb   = (__bf16*)(ws + (512ull << 10));       // 512 KiB
  float*  qb    = (float*)(ws + (2ull << 20));          // 2 MiB
  float*  kb    = (float*)(ws + (4ull << 20));          // 2 MiB
  __bf16* attnw = (__bf16*)(ws + (6ull << 20));         // 2 MiB
  __bf16* mixed = (__bf16*)(ws + (8ull << 20));         // 64 MiB
  __bf16* vbuf  = (__bf16*)(ws + (72ull << 20));        // 64 MiB

  float* out       = (float*)d_out;
  float* attn_mean = out + 33554432ull;
  float* raw_mean  = attn_mean + 131072ull;

  zmap_kernel<<<1024, 256, 0, stream>>>(h_map, zmap);
  qk_gemm<<<dim3(8, 16), 256, 0, stream>>>(zmap, q_w, qb);
  qk_gemm<<<dim3(8, 16), 256, 0, stream>>>(zmap, k_w, kb);
  cvt_kernel<<<128, 256, 0, stream>>>(v_w, vwb);        // zmap now dead
  cvt_kernel<<<128, 256, 0, stream>>>(o_w, owb);
  hipMemsetAsync(attn_mean, 0, 2ull * 131072ull * sizeof(float), stream);
  scores_kernel<<<dim3(32, 64), 256, 0, stream>>>(qb, kb, adj, attnw, attn_mean, raw_mean);
  gemm128<1><<<dim3(4, 512), 256, 0, stream>>>(nullptr, h_val, vwb, vbuf, nullptr, nullptr);
  mix_kernel<<<dim3(64, 64), 256, 0, stream>>>(attnw, vbuf, mixed);
  gemm128<2><<<dim3(4, 512), 256, 0, stream>>>(mixed, nullptr, owb, d_out, h_val, rsc);
}